// Round 20
// baseline (69.429 us; speedup 1.0000x reference)
//
#include <hip/hip_runtime.h>
#include <math.h>

// TopK router via MFMA: logits = x @ W^T + b ; top-2 over E=64 ; sparse softmax.
// x: [T=16384, D=2048] f32, W: [64, 2048] f32, b: [64] f32.
// d_out: [T*64] router probs f32, then [T*2] top-k indices as f32.
//
// R20 = R13 (best, 54.2 us, absmax 0) + NONTEMPORAL x loads. Last untested
// theory after 8 falsified ones (occupancy/barriers/conflicts/B-BW/bursts/
// B-latency-prefetch x2/A-redundancy): per XCD, 128 blocks stream 16 MB of
// x through the 4 MB L2 each pass, evicting the 768 KB WB working set ->
// B "L2 hits" are really L3 misses (~450+ cyc) -> MfmaUtil 12% duty cycle.
// x has zero reuse (read once): __builtin_nontemporal_load (nt flag)
// bypass-streams it, keeping WB L2-resident. Caching hint only -- numerics
// bit-identical to R13 (same cvt, 6-product order, 96-chains, merges at
// chunks 8/16/24/32). Everything else unchanged from R13.
// Sentinels: VGPR ~28, WRITE ~4.2 MB, absmax 0, conflicts ~1.57M.

#define RD 2048
#define RE 64
#define TB 16                    // tokens per block
#define NCH 32                   // chunks of 64 k

typedef __attribute__((ext_vector_type(8))) short bf16x8;
typedef __attribute__((ext_vector_type(4))) float f32x4;
typedef __attribute__((ext_vector_type(4))) unsigned int u32x4;
typedef __attribute__((ext_vector_type(2))) unsigned int u32x2;

__device__ __forceinline__ unsigned short f2b(float f) {  // RNE f32->bf16 bits
    unsigned int u = __float_as_uint(f);
    unsigned int r = ((u >> 16) & 1u) + 0x7fffu;
    return (unsigned short)((u + r) >> 16);
}
__device__ __forceinline__ float b2f(unsigned short h) {
    return __uint_as_float(((unsigned int)h) << 16);
}

// bank-quad XOR swizzle (dword units); involution, preserves 16B alignment
__device__ __forceinline__ int swz(int f) {
    return (f << 2) ^ (((f >> 3) & 7) << 2);
}

// nontemporal f32x4 load (nt: bypass-stream, don't pollute L2)
__device__ __forceinline__ f32x4 ldnt4(const float* p) {
    return __builtin_nontemporal_load((const f32x4*)p);
}

// split 8 floats -> packed bf16 h/l/l2 (4 dwords each) -- wprep only
__device__ __forceinline__ void cvt8(const f32x4 a, const f32x4 bq,
                                     unsigned int* h, unsigned int* l,
                                     unsigned int* l2) {
    float v[8] = {a.x, a.y, a.z, a.w, bq.x, bq.y, bq.z, bq.w};
#pragma unroll
    for (int j = 0; j < 4; ++j) {
        const float a0 = v[2 * j], a1 = v[2 * j + 1];
        const unsigned short h0 = f2b(a0); const float r0 = a0 - b2f(h0);
        const unsigned short h1 = f2b(a1); const float r1 = a1 - b2f(h1);
        const unsigned short m0 = f2b(r0); const float s0 = r0 - b2f(m0);
        const unsigned short m1 = f2b(r1); const float s1 = r1 - b2f(m1);
        const unsigned short q0 = f2b(s0);
        const unsigned short q1 = f2b(s1);
        h[j]  = (unsigned int)h0 | ((unsigned int)h1 << 16);
        l[j]  = (unsigned int)m0 | ((unsigned int)m1 << 16);
        l2[j] = (unsigned int)q0 | ((unsigned int)q1 << 16);
    }
}

// split 4 floats -> packed bf16 h/l/l2 (2 dwords each); same pairing as cvt8
__device__ __forceinline__ void cvt4(const f32x4 a,
                                     unsigned int* h, unsigned int* l,
                                     unsigned int* l2) {
    float v[4] = {a.x, a.y, a.z, a.w};
#pragma unroll
    for (int j = 0; j < 2; ++j) {
        const float a0 = v[2 * j], a1 = v[2 * j + 1];
        const unsigned short h0 = f2b(a0); const float r0 = a0 - b2f(h0);
        const unsigned short h1 = f2b(a1); const float r1 = a1 - b2f(h1);
        const unsigned short m0 = f2b(r0); const float s0 = r0 - b2f(m0);
        const unsigned short m1 = f2b(r1); const float s1 = r1 - b2f(m1);
        const unsigned short q0 = f2b(s0);
        const unsigned short q1 = f2b(s1);
        h[j]  = (unsigned int)h0 | ((unsigned int)h1 << 16);
        l[j]  = (unsigned int)m0 | ((unsigned int)m1 << 16);
        l2[j] = (unsigned int)q0 | ((unsigned int)q1 << 16);
    }
}

// ---------- prep: W -> 3-way bf16 B-fragments (identical to R10-R19) ----------
// WB dword layout: ((ks*4 + et)*3 + comp)*256 + lane*4   (64 ks total)
__global__ __launch_bounds__(256) void wprep_kernel(
    const float* __restrict__ W, unsigned int* __restrict__ WB)
{
    const int ks = blockIdx.x;            // 0..63
    const int et = threadIdx.x >> 6;      // 0..3
    const int lane = threadIdx.x & 63;
    const int e = et * 16 + (lane & 15);
    const int k0 = ks * 32 + (lane >> 4) * 8;
    const float* src = W + (size_t)e * RD + k0;
    const f32x4 a = *(const f32x4*)(src);
    const f32x4 bq = *(const f32x4*)(src + 4);
    unsigned int h[4], l[4], l2[4];
    cvt8(a, bq, h, l, l2);
    unsigned int* dst = WB + (size_t)((ks * 4 + et) * 3) * 256 + lane * 4;
    *(u32x4*)(dst)       = *(u32x4*)h;
    *(u32x4*)(dst + 256) = *(u32x4*)l;
    *(u32x4*)(dst + 512) = *(u32x4*)l2;
}

// ---------- main ----------
__global__ __launch_bounds__(256, 4) void topk_router_kernel(
    const float* __restrict__ x,
    const unsigned int* __restrict__ WB,
    const float* __restrict__ b,
    float* __restrict__ out_router,
    float* __restrict__ out_idx,
    int total_tokens)
{
    const int tid = threadIdx.x;
    const int lane = tid & 63;
    const int et = __builtin_amdgcn_readfirstlane(tid >> 6);  // etile 0..3
    const int tok0 = blockIdx.x * TB;

    // SM[buf][ks][comp][256 dwords] = 12 KB. Aliased as lg[16][66] f64.
    __shared__ __align__(16) unsigned int SM[2][2][3][256];

    // staging map: thread -> (token, 4 consecutive k); 1 f32x4 per step
    const int stok = tid >> 4;            // 0..15
    const int part = tid & 15;            // k-quad within 64-k chunk
    const int tmax = total_tokens - 1;
    const float* gsrc = x + (size_t)min(tok0 + stok, tmax) * RD + part * 4;
    const int s_ks = part >> 3;                            // kstep within chunk
    const int s_f  = ((part >> 1) & 3) * 16 + stok;        // frag lane
    const int s_off = swz(s_f) + (part & 1) * 2;           // swizzled dwords

    f32x4 acc = {0.f, 0.f, 0.f, 0.f};
    double acc64[4] = {0.0, 0.0, 0.0, 0.0};

    // prologue: stage chunk 0, prefetch chunk 1 into regs (nt loads)
    {
        const f32x4 v0 = ldnt4(gsrc);
        unsigned int h[2], l[2], l2[2];
        cvt4(v0, h, l, l2);
        *(u32x2*)&SM[0][s_ks][0][s_off] = *(u32x2*)h;
        *(u32x2*)&SM[0][s_ks][1][s_off] = *(u32x2*)l;
        *(u32x2*)&SM[0][s_ks][2][s_off] = *(u32x2*)l2;
    }
    f32x4 pf = ldnt4(gsrc + 64);
    __syncthreads();

#pragma unroll 1
    for (int c = 0; c < NCH; ++c) {
        const int buf = c & 1;
        // issue chunk c+2's load early (2-deep pipeline, nt)
        const int cn = (c + 2 < NCH) ? (c + 2) : 0;
        const f32x4 nx = ldnt4(gsrc + (size_t)cn * 64);

        // compute chunk c: 2 ksteps x 6 products (this wave's etile)
#pragma unroll
        for (int ks = 0; ks < 2; ++ks) {
            const bf16x8 Ah  = *(const bf16x8*)&SM[buf][ks][0][swz(lane)];
            const bf16x8 Al  = *(const bf16x8*)&SM[buf][ks][1][swz(lane)];
            const bf16x8 Al2 = *(const bf16x8*)&SM[buf][ks][2][swz(lane)];
            const int ksg = c * 2 + ks;
            const unsigned int* wp =
                WB + (size_t)((ksg * 4 + et) * 3) * 256 + lane * 4;
            const bf16x8 Bh  = *(const bf16x8*)(wp);
            const bf16x8 Bl  = *(const bf16x8*)(wp + 256);
            const bf16x8 Bl2 = *(const bf16x8*)(wp + 512);
            acc = __builtin_amdgcn_mfma_f32_16x16x32_bf16(Ah,  Bh,  acc, 0, 0, 0);
            acc = __builtin_amdgcn_mfma_f32_16x16x32_bf16(Ah,  Bl,  acc, 0, 0, 0);
            acc = __builtin_amdgcn_mfma_f32_16x16x32_bf16(Al,  Bh,  acc, 0, 0, 0);
            acc = __builtin_amdgcn_mfma_f32_16x16x32_bf16(Al,  Bl,  acc, 0, 0, 0);
            acc = __builtin_amdgcn_mfma_f32_16x16x32_bf16(Ah,  Bl2, acc, 0, 0, 0);
            acc = __builtin_amdgcn_mfma_f32_16x16x32_bf16(Al2, Bh,  acc, 0, 0, 0);
        }

        // f64 partial merge every 8 chunks (fp32 chains = 96 accumulates;
        // boundaries at chunks 8/16/24/32 -- identical to R10/R13)
        if ((c & 7) == 7) {
            acc64[0] += (double)acc.x; acc64[1] += (double)acc.y;
            acc64[2] += (double)acc.z; acc64[3] += (double)acc.w;
            acc = (f32x4){0.f, 0.f, 0.f, 0.f};
        }

        // write chunk c+1 (prefetched last iteration) into the other buffer
        if (c + 1 < NCH) {
            unsigned int h[2], l[2], l2[2];
            cvt4(pf, h, l, l2);
            const int nbuf = (c + 1) & 1;
            *(u32x2*)&SM[nbuf][s_ks][0][s_off] = *(u32x2*)h;
            *(u32x2*)&SM[nbuf][s_ks][1][s_off] = *(u32x2*)l;
            *(u32x2*)&SM[nbuf][s_ks][2][s_off] = *(u32x2*)l2;
        }
        pf = nx;
        __syncthreads();
    }

    // ---- exchange logits (f64) through LDS (aliases SM; 8.4 KB <= 12 KB) ----
    double* lg = (double*)&SM[0][0][0][0];   // [16 tok][66]
#pragma unroll
    for (int r = 0; r < 4; ++r) {
        const int t = (lane >> 4) * 4 + r;                // C/D row = token
        const int e = et * 16 + (lane & 15);              // C/D col = expert
        lg[(size_t)t * 66 + e] = acc64[r];
    }
    __syncthreads();

    const double bias = (double)b[lane];

    // epilogue (R5-verified): wave et handles tokens [et*4, et*4+4)
#pragma unroll 1
    for (int i = 0; i < 4; ++i) {
        const int t = et * 4 + i;
        const int token = tok0 + t;
        const double v = lg[(size_t)t * 66 + lane] + bias;

        // argmax #1 (value desc, tie -> lower lane)
        double bestv = v;
        int besti = lane;
#pragma unroll
        for (int off = 32; off > 0; off >>= 1) {
            double ov = __shfl_xor(bestv, off, 64);
            int oi = __shfl_xor(besti, off, 64);
            if (ov > bestv || (ov == bestv && oi < besti)) { bestv = ov; besti = oi; }
        }

        // argmax #2 excluding winner
        double v2 = (lane == besti) ? -INFINITY : v;
        double best2v = v2;
        int best2i = lane;
#pragma unroll
        for (int off = 32; off > 0; off >>= 1) {
            double ov = __shfl_xor(best2v, off, 64);
            int oi = __shfl_xor(best2i, off, 64);
            if (ov > best2v || (ov == best2v && oi < best2i)) { best2v = ov; best2i = oi; }
        }

        // 2-element softmax; all other experts exactly 0
        const float e2 = expf((float)(best2v - bestv));
        const float denom = 1.0f + e2;
        const float p1v = 1.0f / denom;
        const float p2v = e2 / denom;

        if (token < total_tokens) {
            float outv = 0.0f;
            if (lane == besti) outv = p1v;
            else if (lane == best2i) outv = p2v;
            out_router[(size_t)token * RE + lane] = outv;
            if (lane == 0) {
                out_idx[(size_t)token * 2 + 0] = (float)besti;
                out_idx[(size_t)token * 2 + 1] = (float)best2i;
            }
        }
    }
}

extern "C" void kernel_launch(void* const* d_in, const int* in_sizes, int n_in,
                              void* d_out, int out_size, void* d_ws, size_t ws_size,
                              hipStream_t stream) {
    const float* x = (const float*)d_in[0];
    const float* W = (const float*)d_in[1];
    const float* b = (const float*)d_in[2];

    const int E = in_sizes[2];                 // 64
    const int D = in_sizes[1] / E;             // 2048
    const int T = in_sizes[0] / D;             // 16384
    (void)E; (void)D;

    unsigned int* WB = (unsigned int*)d_ws;    // 64*4*3*1024 B = 768 KB
    float* out_router = (float*)d_out;
    float* out_idx = out_router + (size_t)T * RE;

    wprep_kernel<<<64, 256, 0, stream>>>(W, WB);

    const int grid = (T + TB - 1) / TB;        // 1024
    topk_router_kernel<<<grid, 256, 0, stream>>>(x, WB, b, out_router, out_idx, T);
}

// Round 21
// 55.006 us; speedup vs baseline: 1.2622x; 1.2622x over previous
//
#include <hip/hip_runtime.h>
#include <math.h>

// TopK router via MFMA: logits = x @ W^T + b ; top-2 over E=64 ; sparse softmax.
// x: [T=16384, D=2048] f32, W: [64, 2048] f32, b: [64] f32.
// d_out: [T*64] router probs f32, then [T*2] top-k indices as f32.
//
// R21 = R13 (best, 54.2 us, absmax 0) + 3-deep x prefetch. R20's nt-load
// regression (+15 us) proved x-load latency is MARGINALLY covered in R13's
// 2-deep pipeline (load at top of c, consumed by ds_write at bottom of
// c+1 ~ 1.5 chunk-walls of flight). Now: hold pf1 (c+1) and pf2 (c+2) in
// named registers, issue c+3's load at top of c -> ~2.5 chunk-walls of
// cover, x latency fully hidden even on L2 miss. Everything else is
// byte-identical to R13: same staging map, same swizzle, same cvt, same
// 6-product MFMA order, same 96-accumulate chains, merges at chunks
// 8/16/24/32, same epilogue. absmax must be exactly 0.
// Sentinels: VGPR ~36 (if 28, the loads were sunk and depth collapsed);
// WRITE ~4.2 MB (no spill); conflicts ~1.57M.

#define RD 2048
#define RE 64
#define TB 16                    // tokens per block
#define NCH 32                   // chunks of 64 k

typedef __attribute__((ext_vector_type(8))) short bf16x8;
typedef __attribute__((ext_vector_type(4))) float f32x4;
typedef __attribute__((ext_vector_type(4))) unsigned int u32x4;
typedef __attribute__((ext_vector_type(2))) unsigned int u32x2;

__device__ __forceinline__ unsigned short f2b(float f) {  // RNE f32->bf16 bits
    unsigned int u = __float_as_uint(f);
    unsigned int r = ((u >> 16) & 1u) + 0x7fffu;
    return (unsigned short)((u + r) >> 16);
}
__device__ __forceinline__ float b2f(unsigned short h) {
    return __uint_as_float(((unsigned int)h) << 16);
}

// bank-quad XOR swizzle (dword units); involution, preserves 16B alignment
__device__ __forceinline__ int swz(int f) {
    return (f << 2) ^ (((f >> 3) & 7) << 2);
}

// split 8 floats -> packed bf16 h/l/l2 (4 dwords each) -- wprep only
__device__ __forceinline__ void cvt8(const f32x4 a, const f32x4 bq,
                                     unsigned int* h, unsigned int* l,
                                     unsigned int* l2) {
    float v[8] = {a.x, a.y, a.z, a.w, bq.x, bq.y, bq.z, bq.w};
#pragma unroll
    for (int j = 0; j < 4; ++j) {
        const float a0 = v[2 * j], a1 = v[2 * j + 1];
        const unsigned short h0 = f2b(a0); const float r0 = a0 - b2f(h0);
        const unsigned short h1 = f2b(a1); const float r1 = a1 - b2f(h1);
        const unsigned short m0 = f2b(r0); const float s0 = r0 - b2f(m0);
        const unsigned short m1 = f2b(r1); const float s1 = r1 - b2f(m1);
        const unsigned short q0 = f2b(s0);
        const unsigned short q1 = f2b(s1);
        h[j]  = (unsigned int)h0 | ((unsigned int)h1 << 16);
        l[j]  = (unsigned int)m0 | ((unsigned int)m1 << 16);
        l2[j] = (unsigned int)q0 | ((unsigned int)q1 << 16);
    }
}

// split 4 floats -> packed bf16 h/l/l2 (2 dwords each); same pairing as cvt8
__device__ __forceinline__ void cvt4(const f32x4 a,
                                     unsigned int* h, unsigned int* l,
                                     unsigned int* l2) {
    float v[4] = {a.x, a.y, a.z, a.w};
#pragma unroll
    for (int j = 0; j < 2; ++j) {
        const float a0 = v[2 * j], a1 = v[2 * j + 1];
        const unsigned short h0 = f2b(a0); const float r0 = a0 - b2f(h0);
        const unsigned short h1 = f2b(a1); const float r1 = a1 - b2f(h1);
        const unsigned short m0 = f2b(r0); const float s0 = r0 - b2f(m0);
        const unsigned short m1 = f2b(r1); const float s1 = r1 - b2f(m1);
        const unsigned short q0 = f2b(s0);
        const unsigned short q1 = f2b(s1);
        h[j]  = (unsigned int)h0 | ((unsigned int)h1 << 16);
        l[j]  = (unsigned int)m0 | ((unsigned int)m1 << 16);
        l2[j] = (unsigned int)q0 | ((unsigned int)q1 << 16);
    }
}

// ---------- prep: W -> 3-way bf16 B-fragments (identical to R10-R20) ----------
// WB dword layout: ((ks*4 + et)*3 + comp)*256 + lane*4   (64 ks total)
__global__ __launch_bounds__(256) void wprep_kernel(
    const float* __restrict__ W, unsigned int* __restrict__ WB)
{
    const int ks = blockIdx.x;            // 0..63
    const int et = threadIdx.x >> 6;      // 0..3
    const int lane = threadIdx.x & 63;
    const int e = et * 16 + (lane & 15);
    const int k0 = ks * 32 + (lane >> 4) * 8;
    const float* src = W + (size_t)e * RD + k0;
    const f32x4 a = *(const f32x4*)(src);
    const f32x4 bq = *(const f32x4*)(src + 4);
    unsigned int h[4], l[4], l2[4];
    cvt8(a, bq, h, l, l2);
    unsigned int* dst = WB + (size_t)((ks * 4 + et) * 3) * 256 + lane * 4;
    *(u32x4*)(dst)       = *(u32x4*)h;
    *(u32x4*)(dst + 256) = *(u32x4*)l;
    *(u32x4*)(dst + 512) = *(u32x4*)l2;
}

// ---------- main ----------
__global__ __launch_bounds__(256, 4) void topk_router_kernel(
    const float* __restrict__ x,
    const unsigned int* __restrict__ WB,
    const float* __restrict__ b,
    float* __restrict__ out_router,
    float* __restrict__ out_idx,
    int total_tokens)
{
    const int tid = threadIdx.x;
    const int lane = tid & 63;
    const int et = __builtin_amdgcn_readfirstlane(tid >> 6);  // etile 0..3
    const int tok0 = blockIdx.x * TB;

    // SM[buf][ks][comp][256 dwords] = 12 KB. Aliased as lg[16][66] f64.
    __shared__ __align__(16) unsigned int SM[2][2][3][256];

    // staging map: thread -> (token, 4 consecutive k); 1 f32x4 per step
    const int stok = tid >> 4;            // 0..15
    const int part = tid & 15;            // k-quad within 64-k chunk
    const int tmax = total_tokens - 1;
    const float* gsrc = x + (size_t)min(tok0 + stok, tmax) * RD + part * 4;
    const int s_ks = part >> 3;                            // kstep within chunk
    const int s_f  = ((part >> 1) & 3) * 16 + stok;        // frag lane
    const int s_off = swz(s_f) + (part & 1) * 2;           // swizzled dwords

    f32x4 acc = {0.f, 0.f, 0.f, 0.f};
    double acc64[4] = {0.0, 0.0, 0.0, 0.0};

    // prologue: stage chunk 0; prefetch chunks 1 and 2 into named regs
    {
        const f32x4 v0 = *(const f32x4*)(gsrc);
        unsigned int h[2], l[2], l2[2];
        cvt4(v0, h, l, l2);
        *(u32x2*)&SM[0][s_ks][0][s_off] = *(u32x2*)h;
        *(u32x2*)&SM[0][s_ks][1][s_off] = *(u32x2*)l;
        *(u32x2*)&SM[0][s_ks][2][s_off] = *(u32x2*)l2;
    }
    f32x4 pf1 = *(const f32x4*)(gsrc + 64);        // chunk 1
    f32x4 pf2 = *(const f32x4*)(gsrc + 128);       // chunk 2
    __syncthreads();

#pragma unroll 1
    for (int c = 0; c < NCH; ++c) {
        const int buf = c & 1;
        // issue chunk c+3's load early (3-deep pipeline)
        const int cn = (c + 3 < NCH) ? (c + 3) : 0;
        const f32x4 nx = *(const f32x4*)(gsrc + (size_t)cn * 64);

        // compute chunk c: 2 ksteps x 6 products (this wave's etile)
#pragma unroll
        for (int ks = 0; ks < 2; ++ks) {
            const bf16x8 Ah  = *(const bf16x8*)&SM[buf][ks][0][swz(lane)];
            const bf16x8 Al  = *(const bf16x8*)&SM[buf][ks][1][swz(lane)];
            const bf16x8 Al2 = *(const bf16x8*)&SM[buf][ks][2][swz(lane)];
            const int ksg = c * 2 + ks;
            const unsigned int* wp =
                WB + (size_t)((ksg * 4 + et) * 3) * 256 + lane * 4;
            const bf16x8 Bh  = *(const bf16x8*)(wp);
            const bf16x8 Bl  = *(const bf16x8*)(wp + 256);
            const bf16x8 Bl2 = *(const bf16x8*)(wp + 512);
            acc = __builtin_amdgcn_mfma_f32_16x16x32_bf16(Ah,  Bh,  acc, 0, 0, 0);
            acc = __builtin_amdgcn_mfma_f32_16x16x32_bf16(Ah,  Bl,  acc, 0, 0, 0);
            acc = __builtin_amdgcn_mfma_f32_16x16x32_bf16(Al,  Bh,  acc, 0, 0, 0);
            acc = __builtin_amdgcn_mfma_f32_16x16x32_bf16(Al,  Bl,  acc, 0, 0, 0);
            acc = __builtin_amdgcn_mfma_f32_16x16x32_bf16(Ah,  Bl2, acc, 0, 0, 0);
            acc = __builtin_amdgcn_mfma_f32_16x16x32_bf16(Al2, Bh,  acc, 0, 0, 0);
        }

        // f64 partial merge every 8 chunks (fp32 chains = 96 accumulates;
        // boundaries at chunks 8/16/24/32 -- identical to R10/R13)
        if ((c & 7) == 7) {
            acc64[0] += (double)acc.x; acc64[1] += (double)acc.y;
            acc64[2] += (double)acc.z; acc64[3] += (double)acc.w;
            acc = (f32x4){0.f, 0.f, 0.f, 0.f};
        }

        // write chunk c+1 (pf1, loaded 2 iterations ago) into the other buffer
        if (c + 1 < NCH) {
            unsigned int h[2], l[2], l2[2];
            cvt4(pf1, h, l, l2);
            const int nbuf = (c + 1) & 1;
            *(u32x2*)&SM[nbuf][s_ks][0][s_off] = *(u32x2*)h;
            *(u32x2*)&SM[nbuf][s_ks][1][s_off] = *(u32x2*)l;
            *(u32x2*)&SM[nbuf][s_ks][2][s_off] = *(u32x2*)l2;
        }
        pf1 = pf2;
        pf2 = nx;
        __syncthreads();
    }

    // ---- exchange logits (f64) through LDS (aliases SM; 8.4 KB <= 12 KB) ----
    double* lg = (double*)&SM[0][0][0][0];   // [16 tok][66]
#pragma unroll
    for (int r = 0; r < 4; ++r) {
        const int t = (lane >> 4) * 4 + r;                // C/D row = token
        const int e = et * 16 + (lane & 15);              // C/D col = expert
        lg[(size_t)t * 66 + e] = acc64[r];
    }
    __syncthreads();

    const double bias = (double)b[lane];

    // epilogue (R5-verified): wave et handles tokens [et*4, et*4+4)
#pragma unroll 1
    for (int i = 0; i < 4; ++i) {
        const int t = et * 4 + i;
        const int token = tok0 + t;
        const double v = lg[(size_t)t * 66 + lane] + bias;

        // argmax #1 (value desc, tie -> lower lane)
        double bestv = v;
        int besti = lane;
#pragma unroll
        for (int off = 32; off > 0; off >>= 1) {
            double ov = __shfl_xor(bestv, off, 64);
            int oi = __shfl_xor(besti, off, 64);
            if (ov > bestv || (ov == bestv && oi < besti)) { bestv = ov; besti = oi; }
        }

        // argmax #2 excluding winner
        double v2 = (lane == besti) ? -INFINITY : v;
        double best2v = v2;
        int best2i = lane;
#pragma unroll
        for (int off = 32; off > 0; off >>= 1) {
            double ov = __shfl_xor(best2v, off, 64);
            int oi = __shfl_xor(best2i, off, 64);
            if (ov > best2v || (ov == best2v && oi < best2i)) { best2v = ov; best2i = oi; }
        }

        // 2-element softmax; all other experts exactly 0
        const float e2 = expf((float)(best2v - bestv));
        const float denom = 1.0f + e2;
        const float p1v = 1.0f / denom;
        const float p2v = e2 / denom;

        if (token < total_tokens) {
            float outv = 0.0f;
            if (lane == besti) outv = p1v;
            else if (lane == best2i) outv = p2v;
            out_router[(size_t)token * RE + lane] = outv;
            if (lane == 0) {
                out_idx[(size_t)token * 2 + 0] = (float)besti;
                out_idx[(size_t)token * 2 + 1] = (float)best2i;
            }
        }
    }
}

extern "C" void kernel_launch(void* const* d_in, const int* in_sizes, int n_in,
                              void* d_out, int out_size, void* d_ws, size_t ws_size,
                              hipStream_t stream) {
    const float* x = (const float*)d_in[0];
    const float* W = (const float*)d_in[1];
    const float* b = (const float*)d_in[2];

    const int E = in_sizes[2];                 // 64
    const int D = in_sizes[1] / E;             // 2048
    const int T = in_sizes[0] / D;             // 16384
    (void)E; (void)D;

    unsigned int* WB = (unsigned int*)d_ws;    // 64*4*3*1024 B = 768 KB
    float* out_router = (float*)d_out;
    float* out_idx = out_router + (size_t)T * RE;

    wprep_kernel<<<64, 256, 0, stream>>>(W, WB);

    const int grid = (T + TB - 1) / TB;        // 1024
    topk_router_kernel<<<grid, 256, 0, stream>>>(x, WB, b, out_router, out_idx, T);
}